// Round 1
// baseline (235.127 us; speedup 1.0000x reference)
//
#include <hip/hip_runtime.h>

typedef __attribute__((ext_vector_type(8))) short bf16x8;
typedef __attribute__((ext_vector_type(4))) float f32x4;
typedef unsigned short u16;

#define MFMA16(a,b,c) __builtin_amdgcn_mfma_f32_16x16x32_bf16((a),(b),(c),0,0,0)

__device__ __forceinline__ u16 f2bf(float f){
  unsigned int u = __float_as_uint(f);
  u += 0x7fffu + ((u >> 16) & 1u);
  return (u16)(u >> 16);
}

__device__ __forceinline__ void gload16(const void* g, void* l){
  __builtin_amdgcn_global_load_lds(
      (__attribute__((address_space(1))) void*)g,
      (__attribute__((address_space(3))) void*)l, 16, 0, 0);
}

// ---------------- prepass: fp32 -> bf16 flat convert ----------------
__global__ __launch_bounds__(256) void mqa_cvt(const float* __restrict__ in,
                                               u16* __restrict__ out, int n8){
  int i = blockIdx.x * 256 + threadIdx.x;
  if (i >= n8) return;
  const float4* p = (const float4*)in;
  float4 a = p[2*i], b = p[2*i+1];
  u16 o[8] = { f2bf(a.x), f2bf(a.y), f2bf(a.z), f2bf(a.w),
               f2bf(b.x), f2bf(b.y), f2bf(b.z), f2bf(b.w) };
  // 16B store
  *(bf16x8*)&out[(size_t)i*8] = *(bf16x8*)o;
}

// ---------------- prepass: transpose-convert  in[R][C] f32 -> out[C][R] bf16
__global__ __launch_bounds__(256) void mqa_tcvt(const float* __restrict__ in,
                                                u16* __restrict__ out, int R, int C){
  __shared__ float t[32][33];
  int c0 = blockIdx.x * 32, r0 = blockIdx.y * 32;
  int x = threadIdx.x & 31, y0 = threadIdx.x >> 5;
  #pragma unroll
  for (int yy = y0; yy < 32; yy += 8)
    t[yy][x] = in[(size_t)(r0 + yy) * C + c0 + x];
  __syncthreads();
  #pragma unroll
  for (int yy = y0; yy < 32; yy += 8)
    out[(size_t)(c0 + yy) * R + r0 + x] = f2bf(t[x][yy]);
}

// ---------------- GEMM: A[M][K] bf16 row-major, Bt[N][K] bf16 row-major ----
// C = A * Bt^T.  EPI 0: write fp32 to outF[M][N].  EPI 1: QKV scatter.
template<int EPI>
__global__ __launch_bounds__(256, 2) void mqa_gemm(
    const u16* __restrict__ A, const u16* __restrict__ Bt,
    float* __restrict__ outF, u16* __restrict__ Qb, u16* __restrict__ Kb,
    u16* __restrict__ Vtb, int M, int N, int K, int NT)
{
  __shared__ __align__(16) u16 lds_a[128*32];
  __shared__ __align__(16) u16 lds_b[128*32];
  int bx = blockIdx.x;
  int mt = bx / NT, nt = bx % NT;
  int m0 = mt * 128, n0 = nt * 128;
  int tid = threadIdx.x;
  int wid = tid >> 6, lane = tid & 63;
  int wrow = (wid >> 1) * 64, wcol = (wid & 1) * 64;
  int lrow = lane >> 2;          // staging: row within 16-row chunk
  int lk   = (lane & 3) * 8;     // staging: k offset (8 bf16 = 16B)
  int fr = lane & 15, g8 = (lane >> 4) * 8, fg = lane >> 4;

  f32x4 acc[4][4];
  #pragma unroll
  for (int i = 0; i < 4; ++i)
    #pragma unroll
    for (int j = 0; j < 4; ++j) acc[i][j] = (f32x4)0.f;

  for (int k0 = 0; k0 < K; k0 += 32) {
    // stage 128x32 A and 128x32 Bt, linear LDS, 16B/lane direct-to-LDS
    #pragma unroll
    for (int c = wid; c < 8; c += 4) {
      gload16(&A [(size_t)(m0 + c*16 + lrow) * K + k0 + lk], &lds_a[c*512]);
      gload16(&Bt[(size_t)(n0 + c*16 + lrow) * K + k0 + lk], &lds_b[c*512]);
    }
    __syncthreads();
    bf16x8 af[4], bf[4];
    #pragma unroll
    for (int i = 0; i < 4; ++i) af[i] = *(const bf16x8*)&lds_a[(wrow + i*16 + fr)*32 + g8];
    #pragma unroll
    for (int j = 0; j < 4; ++j) bf[j] = *(const bf16x8*)&lds_b[(wcol + j*16 + fr)*32 + g8];
    #pragma unroll
    for (int i = 0; i < 4; ++i)
      #pragma unroll
      for (int j = 0; j < 4; ++j)
        acc[i][j] = MFMA16(af[i], bf[j], acc[i][j]);
    __syncthreads();
  }

  // epilogue: C[m][n], row = fg*4+r, col = fr within each 16x16 fragment
  #pragma unroll
  for (int i = 0; i < 4; ++i) {
    #pragma unroll
    for (int j = 0; j < 4; ++j) {
      int ncol = n0 + wcol + j*16 + fr;
      #pragma unroll
      for (int r = 0; r < 4; ++r) {
        int m = m0 + wrow + i*16 + fg*4 + r;
        float v = acc[i][j][r];
        if (EPI == 0) {
          outF[(size_t)m * N + ncol] = v;
        } else {
          u16 bv = f2bf(v);
          if (ncol < 1024) {
            Qb[(size_t)m * 1024 + ncol] = bv;              // Q [B,S,H*HD]
          } else if (ncol < 1088) {
            Kb[(size_t)m * 64 + (ncol - 1024)] = bv;       // K [B,S,HD]
          } else {
            int b = m >> 11, s = m & 2047;                 // Vt [B,HD,S]
            Vtb[((size_t)b * 64 + (ncol - 1088)) * 2048 + s] = bv;
          }
        }
      }
    }
  }
}

// ---------------- flash MQA attention ----------------
// grid (S/128, H, B), 256 threads.  Wave w: q rows [qt*128+w*32, +32)
__global__ __launch_bounds__(256, 2) void mqa_attn(
    const u16* __restrict__ Qb, const u16* __restrict__ Kb,
    const u16* __restrict__ Vtb, u16* __restrict__ Ctx)
{
  const float C1 = 0.18033688011112042f;  // (1/8) * log2(e)
  int qt = blockIdx.x, h = blockIdx.y, b = blockIdx.z;
  int tid = threadIdx.x, wid = tid >> 6, lane = tid & 63;
  int fr = lane & 15, g = lane >> 4;
  int q0 = qt * 128 + wid * 32;

  __shared__ __align__(16) u16 P_lds[128][136];   // pad 128->136: 2-way banks only
  u16 (*Pw)[136] = (u16(*)[136])&P_lds[wid * 32][0];

  const u16* Qbase = Qb + (size_t)b * 2048 * 1024 + (size_t)h * 64;
  const u16* Kbase = Kb + (size_t)b * 2048 * 64;
  const u16* Vbase = Vtb + (size_t)b * 64 * 2048;

  // Q fragments held in registers for the whole kernel
  bf16x8 qf[2][2];
  #pragma unroll
  for (int rf = 0; rf < 2; ++rf)
    #pragma unroll
    for (int ks = 0; ks < 2; ++ks)
      qf[rf][ks] = *(const bf16x8*)&Qbase[(size_t)(q0 + rf*16 + fr) * 1024 + ks*32 + g*8];

  f32x4 oacc[2][4];
  float mrow[2][4], lrow[2][4];
  #pragma unroll
  for (int rf = 0; rf < 2; ++rf) {
    #pragma unroll
    for (int vf = 0; vf < 4; ++vf) oacc[rf][vf] = (f32x4)0.f;
    #pragma unroll
    for (int r = 0; r < 4; ++r) { mrow[rf][r] = -1e30f; lrow[rf][r] = 0.f; }
  }

  for (int kb = 0; kb < 16; ++kb) {
    const int sk0 = kb * 128;
    f32x4 sacc[2][8];
    #pragma unroll
    for (int rf = 0; rf < 2; ++rf)
      #pragma unroll
      for (int cf = 0; cf < 8; ++cf) sacc[rf][cf] = (f32x4)0.f;

    // S = Q K^T (raw, scale folded into exp2)
    #pragma unroll
    for (int ks = 0; ks < 2; ++ks) {
      #pragma unroll
      for (int cf = 0; cf < 8; ++cf) {
        bf16x8 kf = *(const bf16x8*)&Kbase[(size_t)(sk0 + cf*16 + fr) * 64 + ks*32 + g*8];
        sacc[0][cf] = MFMA16(qf[0][ks], kf, sacc[0][cf]);
        sacc[1][cf] = MFMA16(qf[1][ks], kf, sacc[1][cf]);
      }
    }

    // online softmax (rows live in 16-lane groups; reg r -> row g*4+r)
    #pragma unroll
    for (int rf = 0; rf < 2; ++rf) {
      float rs[4];
      #pragma unroll
      for (int r = 0; r < 4; ++r) {
        float mx = sacc[rf][0][r];
        #pragma unroll
        for (int cf = 1; cf < 8; ++cf) mx = fmaxf(mx, sacc[rf][cf][r]);
        #pragma unroll
        for (int off = 1; off < 16; off <<= 1) mx = fmaxf(mx, __shfl_xor(mx, off));
        float mn = fmaxf(mrow[rf][r], mx);
        float corr = __builtin_amdgcn_exp2f((mrow[rf][r] - mn) * C1);
        mrow[rf][r] = mn;
        lrow[rf][r] *= corr;
        #pragma unroll
        for (int vf = 0; vf < 4; ++vf) oacc[rf][vf][r] *= corr;
        rs[r] = 0.f;
      }
      #pragma unroll
      for (int cf = 0; cf < 8; ++cf) {
        #pragma unroll
        for (int r = 0; r < 4; ++r) {
          float p = __builtin_amdgcn_exp2f((sacc[rf][cf][r] - mrow[rf][r]) * C1);
          rs[r] += p;
          Pw[rf*16 + g*4 + r][cf*16 + fr] = f2bf(p);
        }
      }
      #pragma unroll
      for (int r = 0; r < 4; ++r) {
        float t = rs[r];
        #pragma unroll
        for (int off = 1; off < 16; off <<= 1) t += __shfl_xor(t, off);
        lrow[rf][r] += t;
      }
    }

    // ctx += P V   (P from LDS, V^T fragments straight from global/L2)
    #pragma unroll
    for (int ks2 = 0; ks2 < 4; ++ks2) {
      bf16x8 pf0 = *(const bf16x8*)&Pw[fr     ][ks2*32 + g*8];
      bf16x8 pf1 = *(const bf16x8*)&Pw[16 + fr][ks2*32 + g*8];
      #pragma unroll
      for (int vf = 0; vf < 4; ++vf) {
        bf16x8 vfr = *(const bf16x8*)&Vbase[(size_t)(vf*16 + fr) * 2048 + sk0 + ks2*32 + g*8];
        oacc[0][vf] = MFMA16(pf0, vfr, oacc[0][vf]);
        oacc[1][vf] = MFMA16(pf1, vfr, oacc[1][vf]);
      }
    }
  }

  // write ctx [B,S,H*HD] bf16
  #pragma unroll
  for (int rf = 0; rf < 2; ++rf)
    #pragma unroll
    for (int vf = 0; vf < 4; ++vf)
      #pragma unroll
      for (int r = 0; r < 4; ++r) {
        int row = q0 + rf*16 + g*4 + r;
        int col = h*64 + vf*16 + fr;
        Ctx[((size_t)b * 2048 + row) * 1024 + col] = f2bf(oacc[rf][vf][r] / lrow[rf][r]);
      }
}

extern "C" void kernel_launch(void* const* d_in, const int* in_sizes, int n_in,
                              void* d_out, int out_size, void* d_ws, size_t ws_size,
                              hipStream_t stream)
{
  const float* Qin = (const float*)d_in[0];
  const float* Wq  = (const float*)d_in[1];
  const float* Wk  = (const float*)d_in[2];
  const float* Wv  = (const float*)d_in[3];
  const float* Wo  = (const float*)d_in[4];
  float* out = (float*)d_out;

  u16* Xb  = (u16*)d_ws;                 // 4096*1024   Q_input bf16
  u16* WT  = Xb  + (size_t)4096*1024;    // 1152*1024   [Wq^T; Wk^T; Wv^T]
  u16* WoT = WT  + (size_t)1152*1024;    // 1024*1024   Wo^T
  u16* Qb  = WoT + (size_t)1024*1024;    // 4096*1024   Q proj
  u16* Kb  = Qb  + (size_t)4096*1024;    // 4096*64     K proj
  u16* Vtb = Kb  + (size_t)4096*64;      // 2*64*2048   V^T proj
  u16* Ctx = Vtb + (size_t)2*64*2048;    // 4096*1024   attention out

  mqa_cvt<<<2048, 256, 0, stream>>>(Qin, Xb, 4096*1024/8);
  mqa_tcvt<<<dim3(32,32), 256, 0, stream>>>(Wq, WT, 1024, 1024);
  mqa_tcvt<<<dim3(2,32),  256, 0, stream>>>(Wk, WT + (size_t)1024*1024, 1024, 64);
  mqa_tcvt<<<dim3(2,32),  256, 0, stream>>>(Wv, WT + (size_t)1088*1024, 1024, 64);
  mqa_tcvt<<<dim3(32,32), 256, 0, stream>>>(Wo, WoT, 1024, 1024);

  mqa_gemm<1><<<32*9, 256, 0, stream>>>(Xb, WT, nullptr, Qb, Kb, Vtb,
                                        4096, 1152, 1024, 9);
  mqa_attn<<<dim3(16,16,2), 256, 0, stream>>>(Qb, Kb, Vtb, Ctx);
  mqa_gemm<0><<<32*8, 256, 0, stream>>>(Ctx, WoT, out, nullptr, nullptr, nullptr,
                                        4096, 1024, 1024, 8);
}